// Round 9
// baseline (123.648 us; speedup 1.0000x reference)
//
#include <hip/hip_runtime.h>

// GMLoss: bidirectional chamfer min + Geman-McClure penalty (MU=1).
// srcs, tgts: [B=8, D=3, N=4096] fp32. Output: scalar fp32.
//
// R9: 2-launch structure (transform -> fused chamfer+ticketed finish).
//  - R8's finish kernel folded into chamfer: per-block GM sums atomicAdd
//    into 64 cells (2048 adds, ~32/cell - far below R7's fatal 2M); the
//    gticket's last block folds the 64 cells and writes the scalar.
//  - 32-row waves (single A-frag, rmin[16]): VGPR ~64 -> ~8 waves/SIMD
//    (vs 4 at rmin[32]) to hide the MFMA->v_min dependency; butterfly
//    epilogue halves to 80 swizzles. Total MFMA/min/load work unchanged.
//  - K=13 packing + fragment layouts unchanged (absmax 0.0 in R6/R7/R8):
//    A k: [-2sh(3), -2sl(3), -2sh(3), s2h, s2l, 1, 1, 0,0,0]
//    B k: [ th(3),   th(3),   tl(3),  1, 1, t2h, t2l, 0,0,0]
//    dot = |s|^2+|t|^2-2s.t (drops sl.tl ~1e-5 << 1.26e-3 threshold).
//  - Layouts (m74/m101): A[m=lane&31][k=(lane>>5)*8+j], B same (n=lane&31);
//    D: col=lane&31, row=(reg&3)+8*(reg>>2)+4*(lane>>5).

#define NPTS 4096
#define NB   8

typedef __attribute__((ext_vector_type(8)))  short bf16x8;
typedef __attribute__((ext_vector_type(16))) float floatx16;

// ws layout: Apack[srcs], Apack[tgts], Bpack[srcs], Bpack[tgts], cells+ticket
#define OFF_APACK_S 0u
#define OFF_APACK_T (1u << 20)
#define OFF_BPACK_S (2u << 20)
#define OFF_BPACK_T (3u << 20)
#define OFF_RED     (4u << 20)

union V16 { int4 i; bf16x8 h; };

__device__ __forceinline__ unsigned short f2bf(float f) {
    unsigned u = __float_as_uint(f);
    u += 0x7FFFu + ((u >> 16) & 1u);       // RNE
    return (unsigned short)(u >> 16);
}
__device__ __forceinline__ float bf2f(unsigned short h) {
    return __uint_as_float(((unsigned)h) << 16);
}
__device__ __forceinline__ int pk(unsigned short lo, unsigned short hi) {
    return (int)((unsigned)lo | ((unsigned)hi << 16));
}

// ---------------- Kernel 1: pack A-style + B-style for both clouds --------
__device__ __forceinline__ void pack_point(const float* __restrict__ cloud,
                                           int b, int j, int gid,
                                           char* __restrict__ apack,
                                           char* __restrict__ bpack) {
    const unsigned short ONE = 0x3F80;
    const float* p = cloud + b * 3 * NPTS;
    const float x = p[j], y = p[NPTS + j], z = p[2 * NPTS + j];
    const unsigned short hx = f2bf(x), hy = f2bf(y), hz = f2bf(z);
    const unsigned short lx = f2bf(x - bf2f(hx));
    const unsigned short ly = f2bf(y - bf2f(hy));
    const unsigned short lz = f2bf(z - bf2f(hz));
    const unsigned short a0 = f2bf(-2.0f * bf2f(hx));
    const unsigned short a1 = f2bf(-2.0f * bf2f(hy));
    const unsigned short a2 = f2bf(-2.0f * bf2f(hz));
    const unsigned short m0 = f2bf(-2.0f * (x - bf2f(hx)));
    const unsigned short m1 = f2bf(-2.0f * (y - bf2f(hy)));
    const unsigned short m2 = f2bf(-2.0f * (z - bf2f(hz)));
    const float n2 = fmaf(z, z, fmaf(y, y, x * x));
    const unsigned short n2h = f2bf(n2);
    const unsigned short n2l = f2bf(n2 - bf2f(n2h));

    int4* Ap = (int4*)(apack + (size_t)gid * 32);
    Ap[0] = make_int4(pk(a0, a1), pk(a2, m0), pk(m1, m2), pk(a0, a1));
    Ap[1] = make_int4(pk(a2, n2h), pk(n2l, ONE), pk(ONE, 0), 0);

    int4* Bp = (int4*)(bpack + (size_t)gid * 32);
    Bp[0] = make_int4(pk(hx, hy), pk(hz, hx), pk(hy, hz), pk(lx, ly));
    Bp[1] = make_int4(pk(lz, ONE), pk(ONE, n2h), pk(n2l, 0), 0);
}

__global__ __launch_bounds__(256)
void transform_kernel(const float* __restrict__ srcs,
                      const float* __restrict__ tgts,
                      char* __restrict__ ws) {
    const int gid = blockIdx.x * 256 + threadIdx.x;   // b*4096 + j
    const int b = gid >> 12, j = gid & 4095;
    pack_point(srcs, b, j, gid, ws + OFF_APACK_S, ws + OFF_BPACK_S);
    pack_point(tgts, b, j, gid, ws + OFF_APACK_T, ws + OFF_BPACK_T);
    if (gid < 64)  ((float*)(ws + OFF_RED))[gid] = 0.0f;        // cells
    if (gid == 64) *(unsigned*)(ws + OFF_RED + 256) = 0u;       // gticket
}

// ---------------- Kernel 2: row-min MFMA chamfer + ticketed finish --------
__global__ __launch_bounds__(512)
void chamfer_kernel(char* __restrict__ ws, float* __restrict__ out) {
    const int blk    = blockIdx.x;        // 0..2047
    const int dir    = blk >> 10;
    const int rem    = blk & 1023;
    const int b      = rem >> 7;
    const int stripe = rem & 127;         // 32 query rows
    const int tid    = threadIdx.x;
    const int wave   = tid >> 6;          // 0..7
    const int lane   = tid & 63;
    const int l31    = lane & 31;
    const int half   = lane >> 5;

    const char* Ap = ws + (dir == 0 ? OFF_APACK_S : OFF_APACK_T);
    const char* Bp = ws + (dir == 0 ? OFF_BPACK_T : OFF_BPACK_S);
    float*    cells   = (float*)(ws + OFF_RED);
    unsigned* gticket = (unsigned*)(ws + OFF_RED + 256);

    V16 av;
    av.i = *(const int4*)(Ap + (size_t)(b * NPTS + stripe * 32 + l31) * 32 + half * 16);

    floatx16 rmin, zero;
#pragma unroll
    for (int r = 0; r < 16; r++) { rmin[r] = 3.0e38f; zero[r] = 0.0f; }

    const int ct0 = wave * 16;            // 16 col-tiles per wave
    const char* bbase = Bp + (size_t)(b * NPTS + ct0 * 32 + l31) * 32 + half * 16;

    // depth-4 register prefetch ring; wrap (&15) reloads L1-hot head at tail
    V16 t0, t1, t2, t3;
    t0.i = *(const int4*)(bbase);
    t1.i = *(const int4*)(bbase + 1024);
    t2.i = *(const int4*)(bbase + 2048);
    t3.i = *(const int4*)(bbase + 3072);

#pragma unroll
    for (int i = 0; i < 16; i += 4) {
        V16 n0, n1, n2, n3;
        n0.i = *(const int4*)(bbase + (size_t)((i + 4) & 15) * 1024);
        n1.i = *(const int4*)(bbase + (size_t)((i + 5) & 15) * 1024);
        n2.i = *(const int4*)(bbase + (size_t)((i + 6) & 15) * 1024);
        n3.i = *(const int4*)(bbase + (size_t)((i + 7) & 15) * 1024);
#pragma unroll
        for (int u = 0; u < 4; u++) {
            const bf16x8 bf = (u == 0 ? t0.h : u == 1 ? t1.h : u == 2 ? t2.h : t3.h);
            const floatx16 d =
                __builtin_amdgcn_mfma_f32_32x32x16_bf16(av.h, bf, zero, 0, 0, 0);
#pragma unroll
            for (int r = 0; r < 16; r++) rmin[r] = fminf(rmin[r], d[r]);
        }
        t0 = n0; t1 = n1; t2 = n2; t3 = n3;
    }

    // ---- butterfly min over the 32 col-lanes ----
#pragma unroll
    for (int off = 1; off < 32; off <<= 1) {
#pragma unroll
        for (int r = 0; r < 16; r++)
            rmin[r] = fminf(rmin[r], __shfl_xor(rmin[r], off, 64));
    }
    __shared__ float sRow[8][32];
    if (l31 == 0) {                       // lanes 0 and 32
#pragma unroll
        for (int r = 0; r < 16; r++)
            sRow[wave][(r & 3) + 8 * (r >> 2) + 4 * half] = rmin[r];
    }
    __syncthreads();

    float g = 0.0f;
    if (tid < 32) {
        float m = 3.0e38f;
#pragma unroll
        for (int w = 0; w < 8; w++) m = fminf(m, sRow[w][tid]);
        m = fmaxf(m, 0.0f);
        g = m / (m + 1.0f);               // GM, MU=1
#pragma unroll
        for (int off = 1; off < 32; off <<= 1)
            g += __shfl_xor(g, off, 64);
    }

    // ---- ticketed finish (wave 0 only) ----
    int last = 0;
    if (tid == 0) {
        atomicAdd(&cells[blk & 63], g);   // 2048 adds over 64 cells
        __threadfence();
        last = (atomicAdd(gticket, 1u) == 2047u) ? 1 : 0;
    }
    if (tid < 64) {
        last = __shfl(last, 0, 64);
        if (last) {
            __threadfence();
            float v = atomicAdd(&cells[tid], 0.0f);   // coherent read
#pragma unroll
            for (int off = 1; off < 64; off <<= 1)
                v += __shfl_xor(v, off, 64);
            if (tid == 0) out[0] = v * (1.0f / (NB * NPTS));
        }
    }
}

extern "C" void kernel_launch(void* const* d_in, const int* in_sizes, int n_in,
                              void* d_out, int out_size, void* d_ws, size_t ws_size,
                              hipStream_t stream) {
    const float* srcs = (const float*)d_in[0];
    const float* tgts = (const float*)d_in[1];
    float* out = (float*)d_out;
    char* ws = (char*)d_ws;

    transform_kernel<<<dim3(128), dim3(256), 0, stream>>>(srcs, tgts, ws);
    chamfer_kernel<<<dim3(2048), dim3(512), 0, stream>>>(ws, out);
}

// Round 10
// 79.435 us; speedup vs baseline: 1.5566x; 1.5566x over previous
//
#include <hip/hip_runtime.h>

// GMLoss: bidirectional chamfer min + Geman-McClure penalty (MU=1).
// srcs, tgts: [B=8, D=3, N=4096] fp32. Output: scalar fp32.
//
// R10 = R8 (best: 80.4us, 3 kernels, plain stores, NO in-kernel tickets --
// R7/R9 proved device atomics/fences in the hot kernel cost tens of us)
// + ONE change: XCD-aware block swizzle in chamfer.
//   R8 mapped 64 CONSECUTIVE blocks to one (dir,b) Bpack -> round-robin
//   block->XCD dispatch made every XCD stream all 16 Bpacks (16MB) through
//   its 4MB L2 -> thrash -> L3-latency loads. Now group = blk & 15: each
//   XCD holds only ~2 groups (2MB), B-streams stay L2-resident.
//
// K=13 packing (absmax 0.0 in R6-R9):
//   A k: [-2sh(3), -2sl(3), -2sh(3), s2h, s2l, 1, 1, 0,0,0]
//   B k: [ th(3),   th(3),   tl(3),  1, 1, t2h, t2l, 0,0,0]
//   dot = |s|^2+|t|^2-2s.t (drops sl.tl ~1e-5 << 1.26e-3 threshold).
// Layouts (m74/m101): A[m=lane&31][k=(lane>>5)*8+j], B same (n=lane&31);
// D: col=lane&31, row=(reg&3)+8*(reg>>2)+4*(lane>>5).

#define NPTS 4096
#define NB   8

typedef __attribute__((ext_vector_type(8)))  short bf16x8;
typedef __attribute__((ext_vector_type(16))) float floatx16;

// ws layout: Apack[srcs], Apack[tgts], Bpack[srcs], Bpack[tgts], bsum
#define OFF_APACK_S 0u
#define OFF_APACK_T (1u << 20)
#define OFF_BPACK_S (2u << 20)
#define OFF_BPACK_T (3u << 20)
#define OFF_BSUM    (4u << 20)

union V16 { int4 i; bf16x8 h; };

__device__ __forceinline__ unsigned short f2bf(float f) {
    unsigned u = __float_as_uint(f);
    u += 0x7FFFu + ((u >> 16) & 1u);       // RNE
    return (unsigned short)(u >> 16);
}
__device__ __forceinline__ float bf2f(unsigned short h) {
    return __uint_as_float(((unsigned)h) << 16);
}
__device__ __forceinline__ int pk(unsigned short lo, unsigned short hi) {
    return (int)((unsigned)lo | ((unsigned)hi << 16));
}

// ---------------- Kernel 1: pack A-style + B-style for both clouds --------
__device__ __forceinline__ void pack_point(const float* __restrict__ cloud,
                                           int b, int j, int gid,
                                           char* __restrict__ apack,
                                           char* __restrict__ bpack) {
    const unsigned short ONE = 0x3F80;
    const float* p = cloud + b * 3 * NPTS;
    const float x = p[j], y = p[NPTS + j], z = p[2 * NPTS + j];
    const unsigned short hx = f2bf(x), hy = f2bf(y), hz = f2bf(z);
    const unsigned short lx = f2bf(x - bf2f(hx));
    const unsigned short ly = f2bf(y - bf2f(hy));
    const unsigned short lz = f2bf(z - bf2f(hz));
    const unsigned short a0 = f2bf(-2.0f * bf2f(hx));
    const unsigned short a1 = f2bf(-2.0f * bf2f(hy));
    const unsigned short a2 = f2bf(-2.0f * bf2f(hz));
    const unsigned short m0 = f2bf(-2.0f * (x - bf2f(hx)));
    const unsigned short m1 = f2bf(-2.0f * (y - bf2f(hy)));
    const unsigned short m2 = f2bf(-2.0f * (z - bf2f(hz)));
    const float n2 = fmaf(z, z, fmaf(y, y, x * x));
    const unsigned short n2h = f2bf(n2);
    const unsigned short n2l = f2bf(n2 - bf2f(n2h));

    int4* Ap = (int4*)(apack + (size_t)gid * 32);
    Ap[0] = make_int4(pk(a0, a1), pk(a2, m0), pk(m1, m2), pk(a0, a1));
    Ap[1] = make_int4(pk(a2, n2h), pk(n2l, ONE), pk(ONE, 0), 0);

    int4* Bp = (int4*)(bpack + (size_t)gid * 32);
    Bp[0] = make_int4(pk(hx, hy), pk(hz, hx), pk(hy, hz), pk(lx, ly));
    Bp[1] = make_int4(pk(lz, ONE), pk(ONE, n2h), pk(n2l, 0), 0);
}

__global__ __launch_bounds__(256)
void transform_kernel(const float* __restrict__ srcs,
                      const float* __restrict__ tgts,
                      char* __restrict__ ws) {
    const int gid = blockIdx.x * 256 + threadIdx.x;   // b*4096 + j
    const int b = gid >> 12, j = gid & 4095;
    pack_point(srcs, b, j, gid, ws + OFF_APACK_S, ws + OFF_BPACK_S);
    pack_point(tgts, b, j, gid, ws + OFF_APACK_T, ws + OFF_BPACK_T);
}

// ---------------- Kernel 2: row-min-only MFMA chamfer ----------------
__global__ __launch_bounds__(512, 4)
void chamfer_kernel(char* __restrict__ ws) {
    const int blk    = blockIdx.x;        // 0..1023
    // XCD-aware swizzle: consecutive blocks cycle through the 16 (dir,b)
    // groups so each XCD's L2 only ever holds ~2 Bpacks (2MB < 4MB).
    const int group  = blk & 15;
    const int dir    = group >> 3;
    const int b      = group & 7;
    const int stripe = blk >> 4;          // 0..63, 64 query rows each
    const int tid    = threadIdx.x;
    const int wave   = tid >> 6;          // 0..7
    const int lane   = tid & 63;
    const int l31    = lane & 31;
    const int half   = lane >> 5;

    const char* Ap = ws + (dir == 0 ? OFF_APACK_S : OFF_APACK_T);
    const char* Bp = ws + (dir == 0 ? OFF_BPACK_T : OFF_BPACK_S);

    V16 av0, av1;
    av0.i = *(const int4*)(Ap + (size_t)(b * NPTS + stripe * 64 + l31) * 32 + half * 16);
    av1.i = *(const int4*)(Ap + (size_t)(b * NPTS + stripe * 64 + 32 + l31) * 32 + half * 16);

    floatx16 rmin0, rmin1, zero;
#pragma unroll
    for (int r = 0; r < 16; r++) { rmin0[r] = 3.0e38f; rmin1[r] = 3.0e38f; zero[r] = 0.0f; }

    const int ct0 = wave * 16;            // 16 col-tiles per wave
    const char* bbase = Bp + (size_t)(b * NPTS + ct0 * 32 + l31) * 32 + half * 16;

    // depth-4 register prefetch ring; wrap (&15) reloads L1-hot head at tail
    V16 t0, t1, t2, t3;
    t0.i = *(const int4*)(bbase);
    t1.i = *(const int4*)(bbase + 1024);
    t2.i = *(const int4*)(bbase + 2048);
    t3.i = *(const int4*)(bbase + 3072);

#pragma unroll
    for (int i = 0; i < 16; i += 4) {
        V16 n0, n1, n2, n3;
        n0.i = *(const int4*)(bbase + (size_t)((i + 4) & 15) * 1024);
        n1.i = *(const int4*)(bbase + (size_t)((i + 5) & 15) * 1024);
        n2.i = *(const int4*)(bbase + (size_t)((i + 6) & 15) * 1024);
        n3.i = *(const int4*)(bbase + (size_t)((i + 7) & 15) * 1024);
#pragma unroll
        for (int u = 0; u < 4; u++) {
            const bf16x8 bf = (u == 0 ? t0.h : u == 1 ? t1.h : u == 2 ? t2.h : t3.h);
            const floatx16 d0 =
                __builtin_amdgcn_mfma_f32_32x32x16_bf16(av0.h, bf, zero, 0, 0, 0);
            const floatx16 d1 =
                __builtin_amdgcn_mfma_f32_32x32x16_bf16(av1.h, bf, zero, 0, 0, 0);
#pragma unroll
            for (int r = 0; r < 16; r++) {
                rmin0[r] = fminf(rmin0[r], d0[r]);
                rmin1[r] = fminf(rmin1[r], d1[r]);
            }
        }
        t0 = n0; t1 = n1; t2 = n2; t3 = n3;
    }

    // ---- butterfly min over the 32 col-lanes ----
#pragma unroll
    for (int off = 1; off < 32; off <<= 1) {
#pragma unroll
        for (int r = 0; r < 16; r++) {
            rmin0[r] = fminf(rmin0[r], __shfl_xor(rmin0[r], off, 64));
            rmin1[r] = fminf(rmin1[r], __shfl_xor(rmin1[r], off, 64));
        }
    }
    __shared__ float sRow[8][64];
    if (l31 == 0) {                       // lanes 0 and 32
#pragma unroll
        for (int r = 0; r < 16; r++) {
            const int row = (r & 3) + 8 * (r >> 2) + 4 * half;
            sRow[wave][row]      = rmin0[r];
            sRow[wave][32 + row] = rmin1[r];
        }
    }
    __syncthreads();
    if (tid < 64) {
        float m = 3.0e38f;
#pragma unroll
        for (int w = 0; w < 8; w++) m = fminf(m, sRow[w][tid]);
        m = fmaxf(m, 0.0f);
        float g = m / (m + 1.0f);         // GM, MU=1
#pragma unroll
        for (int off = 1; off < 64; off <<= 1)
            g += __shfl_xor(g, off, 64);
        if (tid == 0)
            ((float*)(ws + OFF_BSUM))[blk] = g;   // plain store, no atomics
    }
}

// ---------------- Kernel 3: single-block finish ----------------
__global__ __launch_bounds__(256)
void finish_kernel(const char* __restrict__ ws, float* __restrict__ out) {
    const float* bsum = (const float*)(ws + OFF_BSUM);
    const int tid = threadIdx.x;
    float g = bsum[tid] + bsum[tid + 256] + bsum[tid + 512] + bsum[tid + 768];
#pragma unroll
    for (int off = 1; off < 64; off <<= 1)
        g += __shfl_xor(g, off, 64);
    __shared__ float sp[4];
    if ((tid & 63) == 0) sp[tid >> 6] = g;
    __syncthreads();
    if (tid == 0)
        out[0] = (sp[0] + sp[1] + sp[2] + sp[3]) * (1.0f / (NB * NPTS));
}

extern "C" void kernel_launch(void* const* d_in, const int* in_sizes, int n_in,
                              void* d_out, int out_size, void* d_ws, size_t ws_size,
                              hipStream_t stream) {
    const float* srcs = (const float*)d_in[0];
    const float* tgts = (const float*)d_in[1];
    float* out = (float*)d_out;
    char* ws = (char*)d_ws;

    transform_kernel<<<dim3(128), dim3(256), 0, stream>>>(srcs, tgts, ws);
    chamfer_kernel<<<dim3(1024), dim3(512), 0, stream>>>(ws);
    finish_kernel<<<dim3(1), dim3(256), 0, stream>>>(ws, out);
}